// Round 1
// baseline (435.412 us; speedup 1.0000x reference)
//
#include <hip/hip_runtime.h>
#include <cstdint>
#include <cstddef>

#define EPSV 1e-5f

// ---------------------------------------------------------------------------
// Fold BN (+conv bias) into per-channel scale/shift.
// prm layout (floats): [0:128) ascale, [128:256) ashift,
//                      [256:512) escale, [512:768) eshift,
//                      [768:896) bscale (4x32), [896:1024) bshift (4x32)
// ---------------------------------------------------------------------------
__global__ __launch_bounds__(256) void prep_params(
    const float* __restrict__ rwb, const float* __restrict__ rg,
    const float* __restrict__ rb,  const float* __restrict__ rm,
    const float* __restrict__ rv,
    const float* __restrict__ ewb, const float* __restrict__ eg,
    const float* __restrict__ eb,  const float* __restrict__ em,
    const float* __restrict__ ev,
    const float* __restrict__ bg,  const float* __restrict__ bb,
    const float* __restrict__ bm,  const float* __restrict__ bv,
    float* __restrict__ prm)
{
    int t = threadIdx.x;  // 0..255
    if (t < 128) {
        float sc = rg[t] * rsqrtf(rv[t] + EPSV);
        prm[t]       = sc;
        prm[128 + t] = rb[t] - rm[t] * sc + rwb[t] * sc;   // conv bias folded
        float bsc = bg[t] * rsqrtf(bv[t] + EPSV);
        prm[768 + t] = bsc;
        prm[896 + t] = bb[t] - bm[t] * bsc;                // gcn bias NOT here (pre-mix)
    }
    {
        float sc = eg[t] * rsqrtf(ev[t] + EPSV);
        prm[256 + t] = sc;
        prm[512 + t] = eb[t] - em[t] * sc + ewb[t] * sc;
    }
}

// ---------------------------------------------------------------------------
// Batched pointwise conv as GEMM + BN + (residual) + ReLU.
// In : [NB][Cin][P]  (per-sample matrices, row stride P)
// Wt : [O][Cin]
// Out[n][o][p] = relu( (sum_c Wt[o][c]*In[n][c][p]) * scale[o] + shift[o]
//                      + (resid ? resid[n][o][p] : 0) )
// Block: 256 threads, tile 128(o) x 128(p), 8x8 per-thread register tile,
// fragments interleaved stride-16 for conflict-free LDS reads.
// ---------------------------------------------------------------------------
__global__ __launch_bounds__(256) void gemm_bn_relu(
    const float* __restrict__ In, const float* __restrict__ Wt,
    const float* __restrict__ scale, const float* __restrict__ shift,
    const float* __restrict__ resid, float* __restrict__ Out,
    int Cin, int O, int P)
{
    const int n  = blockIdx.z;
    const int p0 = blockIdx.x * 128;
    const int o0 = blockIdx.y * 128;
    const int tid = threadIdx.x;
    const int tx = tid & 15;   // pixel fragment
    const int ty = tid >> 4;   // output fragment

    __shared__ float xs[32][128];   // [k][p]
    __shared__ float ws[128][33];   // [o][k], padded to kill bank conflicts

    float acc[8][8];
    #pragma unroll
    for (int i = 0; i < 8; ++i)
        #pragma unroll
        for (int j = 0; j < 8; ++j) acc[i][j] = 0.f;

    const float* inn = In + (size_t)n * Cin * P;

    for (int kc = 0; kc < Cin; kc += 32) {
        // stage xs: 32 rows x 128 pixels (float4, coalesced)
        {
            int r0  = tid >> 5;            // 0..7
            int col = (tid & 31) << 2;     // 0..124
            int p   = p0 + col;
            #pragma unroll
            for (int rr = 0; rr < 4; ++rr) {
                int r = r0 + rr * 8;
                float4 v = make_float4(0.f, 0.f, 0.f, 0.f);
                if (p + 3 < P)
                    v = *(const float4*)(inn + (size_t)(kc + r) * P + p);
                *(float4*)(&xs[r][col]) = v;
            }
        }
        // stage ws: 128 rows x 32 k
        {
            int r0 = tid >> 3;             // 0..31
            int c4 = (tid & 7) << 2;       // 0..28
            #pragma unroll
            for (int rr = 0; rr < 4; ++rr) {
                int o = r0 + rr * 32;
                float4 v = *(const float4*)(Wt + (size_t)(o0 + o) * Cin + kc + c4);
                ws[o][c4]     = v.x;
                ws[o][c4 + 1] = v.y;
                ws[o][c4 + 2] = v.z;
                ws[o][c4 + 3] = v.w;
            }
        }
        __syncthreads();

        for (int k = 0; k < 32; ++k) {
            float a[8], b[8];
            #pragma unroll
            for (int i = 0; i < 8; ++i) a[i] = ws[ty + i * 16][k];
            #pragma unroll
            for (int j = 0; j < 8; ++j) b[j] = xs[k][tx + j * 16];
            #pragma unroll
            for (int i = 0; i < 8; ++i)
                #pragma unroll
                for (int j = 0; j < 8; ++j)
                    acc[i][j] = fmaf(a[i], b[j], acc[i][j]);
        }
        __syncthreads();
    }

    // epilogue: BN + residual + ReLU
    #pragma unroll
    for (int i = 0; i < 8; ++i) {
        int o = o0 + ty + i * 16;
        float sc = scale[o], sh = shift[o];
        size_t base = ((size_t)n * O + o) * P;
        #pragma unroll
        for (int j = 0; j < 8; ++j) {
            int p = p0 + tx + j * 16;
            if (p < P) {
                float v = fmaf(acc[i][j], sc, sh);
                if (resid) v += resid[base + p];
                Out[base + p] = fmaxf(v, 0.f);
            }
        }
    }
}

// ---------------------------------------------------------------------------
// One res2net branch step (fused conv 32->96, adjacency mix over v, BN, ReLU).
// Block: (t-tile of 8, n). 256 threads: thread owns (c = tid&31, tl = tid>>5).
// sp_in = h[:, i*32:(i+1)*32] + (i>0 ? outs[:, (i-1)*32:i*32] : 0)
// g[k][v] = gcn_b[k*32+c] + sum_cin gw[k*32+c][cin] * sp_in[cin][t][v]
// out[w]  = sum_k sum_v g[k][v] * (A+PA)[k][v][w];  BN+ReLU; write outs chunk i
// ---------------------------------------------------------------------------
__global__ __launch_bounds__(256) void gcn_step(
    const float* __restrict__ h,      // [64][128][1600]
    float* __restrict__ outs,         // [64][128][1600]
    const float* __restrict__ gw,     // [96][32]   (step i slice)
    const float* __restrict__ gb,     // [96]
    const float* __restrict__ Aadj,   // [3][25][25]
    const float* __restrict__ PAi,    // [3][25][25] (step i slice)
    const float* __restrict__ bscale, // [32]
    const float* __restrict__ bshift, // [32]
    int step)
{
    const int n  = blockIdx.y;
    const int tt = blockIdx.x;          // 0..7 (t-tiles of 8)
    const int tid = threadIdx.x;
    const int c  = tid & 31;
    const int tl = tid >> 5;            // 0..7

    __shared__ float sp[32 * 200];      // [cin][tl*25+v]
    __shared__ float wsg[96][33];       // gcn weights, padded
    __shared__ float Mm[3][25][28];     // A+PA, rows padded to 28 (16B aligned)

    const size_t pbase = (size_t)tt * 200;
    const float* hch = h + ((size_t)n * 128 + (size_t)step * 32) * 1600 + pbase;
    const float* pch = (step > 0)
        ? outs + ((size_t)n * 128 + (size_t)(step - 1) * 32) * 1600 + pbase
        : nullptr;

    for (int idx = tid; idx < 32 * 200; idx += 256) {
        int cin = idx / 200, pp = idx % 200;
        float v = hch[(size_t)cin * 1600 + pp];
        if (pch) v += pch[(size_t)cin * 1600 + pp];
        sp[idx] = v;
    }
    for (int idx = tid; idx < 96 * 32; idx += 256)
        wsg[idx >> 5][idx & 31] = gw[idx];
    for (int idx = tid; idx < 3 * 625; idx += 256) {
        int k = idx / 625, rem = idx % 625;
        Mm[k][rem / 25][rem % 25] = Aadj[idx] + PAi[idx];
    }
    __syncthreads();

    // phase 1: conv into registers
    float g[3][25];
    {
        float b0 = gb[c], b1 = gb[32 + c], b2 = gb[64 + c];
        #pragma unroll
        for (int v = 0; v < 25; ++v) { g[0][v] = b0; g[1][v] = b1; g[2][v] = b2; }
    }
    for (int cin = 0; cin < 32; ++cin) {
        float w0 = wsg[c][cin], w1 = wsg[32 + c][cin], w2 = wsg[64 + c][cin];
        const float* s = &sp[cin * 200 + tl * 25];
        #pragma unroll
        for (int v = 0; v < 25; ++v) {
            float sv = s[v];
            g[0][v] = fmaf(w0, sv, g[0][v]);
            g[1][v] = fmaf(w1, sv, g[1][v]);
            g[2][v] = fmaf(w2, sv, g[2][v]);
        }
    }

    // phase 2: adjacency mix (Mm reads are wave-uniform -> broadcast)
    float out[25];
    #pragma unroll
    for (int w = 0; w < 25; ++w) out[w] = 0.f;
    #pragma unroll
    for (int k = 0; k < 3; ++k)
        #pragma unroll
        for (int v = 0; v < 25; ++v) {
            float gv = g[k][v];
            #pragma unroll
            for (int w = 0; w < 25; ++w)
                out[w] = fmaf(gv, Mm[k][v][w], out[w]);
        }

    // phase 3: BN + ReLU, stage through LDS for coalesced global store
    float sc = bscale[c], sh = bshift[c];
    __syncthreads();   // everyone done reading sp
    #pragma unroll
    for (int w = 0; w < 25; ++w)
        sp[c * 200 + tl * 25 + w] = fmaxf(fmaf(out[w], sc, sh), 0.f);
    __syncthreads();

    float* och = outs + ((size_t)n * 128 + (size_t)step * 32) * 1600 + pbase;
    for (int idx = tid; idx < 32 * 200; idx += 256)
        och[(size_t)(idx / 200) * 1600 + (idx % 200)] = sp[idx];
}

// ---------------------------------------------------------------------------
extern "C" void kernel_launch(void* const* d_in, const int* in_sizes, int n_in,
                              void* d_out, int out_size, void* d_ws, size_t ws_size,
                              hipStream_t stream)
{
    const float* x   = (const float*)d_in[0];   // [64][256][64][25]
    const float* A   = (const float*)d_in[1];   // [3][25][25]
    const float* rw  = (const float*)d_in[2];   // [128][256]
    const float* rwb = (const float*)d_in[3];   // [128]
    const float* rg  = (const float*)d_in[4];
    const float* rb  = (const float*)d_in[5];
    const float* rm  = (const float*)d_in[6];
    const float* rv  = (const float*)d_in[7];
    const float* gw  = (const float*)d_in[8];   // [4][96][32]
    const float* gb  = (const float*)d_in[9];   // [4][96]
    const float* PA  = (const float*)d_in[10];  // [4][3][25][25]
    const float* bg  = (const float*)d_in[11];  // [4][32]
    const float* bb  = (const float*)d_in[12];
    const float* bm  = (const float*)d_in[13];
    const float* bv  = (const float*)d_in[14];
    const float* ew  = (const float*)d_in[15];  // [256][128]
    const float* ewb = (const float*)d_in[16];  // [256]
    const float* eg  = (const float*)d_in[17];
    const float* eb  = (const float*)d_in[18];
    const float* em  = (const float*)d_in[19];
    const float* ev  = (const float*)d_in[20];

    float* wsf  = (float*)d_ws;
    float* h    = wsf;                    // 64*128*1600 = 13,107,200 floats
    float* outs = wsf + 13107200;         // 13,107,200 floats
    float* prm  = wsf + 26214400;         // 1024 floats

    prep_params<<<1, 256, 0, stream>>>(rwb, rg, rb, rm, rv,
                                       ewb, eg, eb, em, ev,
                                       bg, bb, bm, bv, prm);

    // reduct conv + BN + ReLU : x[64][256][1600] -> h[64][128][1600]
    gemm_bn_relu<<<dim3(13, 1, 64), 256, 0, stream>>>(
        x, rw, prm, prm + 128, nullptr, h, 256, 128, 1600);

    // 4 sequential res2net branches
    for (int i = 0; i < 4; ++i) {
        gcn_step<<<dim3(8, 64), 256, 0, stream>>>(
            h, outs, gw + (size_t)i * 96 * 32, gb + (size_t)i * 96,
            A, PA + (size_t)i * 3 * 625,
            prm + 768 + i * 32, prm + 896 + i * 32, i);
    }

    // expand conv + BN + residual + ReLU : outs -> d_out
    gemm_bn_relu<<<dim3(13, 2, 64), 256, 0, stream>>>(
        outs, ew, prm + 256, prm + 512, x, (float*)d_out, 128, 256, 1600);
}

// Round 4
// 340.492 us; speedup vs baseline: 1.2788x; 1.2788x over previous
//
#include <hip/hip_runtime.h>
#include <cstdint>
#include <cstddef>

#define EPSV 1e-5f

using f32x4  = __attribute__((ext_vector_type(4))) float;
using bf16x8 = __attribute__((ext_vector_type(8))) short;

// RNE pack of two f32 into two bf16 (lo -> low16, hi -> high16)
static __device__ __forceinline__ unsigned pk2(float lo, float hi) {
    unsigned a = __builtin_bit_cast(unsigned, lo);
    unsigned b = __builtin_bit_cast(unsigned, hi);
    a = (a + 0x7FFFu + ((a >> 16) & 1u)) >> 16;
    b = (b + 0x7FFFu + ((b >> 16) & 1u)) & 0xFFFF0000u;
    return a | b;
}

// ---------------------------------------------------------------------------
__global__ __launch_bounds__(256) void prep_params(
    const float* __restrict__ rwb, const float* __restrict__ rg,
    const float* __restrict__ rb,  const float* __restrict__ rm,
    const float* __restrict__ rv,
    const float* __restrict__ ewb, const float* __restrict__ eg,
    const float* __restrict__ eb,  const float* __restrict__ em,
    const float* __restrict__ ev,
    const float* __restrict__ bg,  const float* __restrict__ bb,
    const float* __restrict__ bm,  const float* __restrict__ bv,
    float* __restrict__ prm)
{
    int t = threadIdx.x;
    if (t < 128) {
        float sc = rg[t] * rsqrtf(rv[t] + EPSV);
        prm[t]       = sc;
        prm[128 + t] = rb[t] - rm[t] * sc + rwb[t] * sc;
        float bsc = bg[t] * rsqrtf(bv[t] + EPSV);
        prm[768 + t] = bsc;
        prm[896 + t] = bb[t] - bm[t] * bsc;
    }
    {
        float sc = eg[t] * rsqrtf(ev[t] + EPSV);
        prm[256 + t] = sc;
        prm[512 + t] = eb[t] - em[t] * sc + ewb[t] * sc;
    }
}

// ---------------------------------------------------------------------------
// bf16 MFMA batched GEMM + BN + (residual) + ReLU.
// In  [NB][Cin][P] f32, Wt [O][Cin] f32, Out [NB][O][P] f32.
// 256 thr (4 waves 2x2), tile 128(o) x 128(p), BK=32, double-buffered LDS.
// sA[o][k], sB[p][k], row stride 40 bf16 (80 B, 16B-aligned).
// Fragments: lane holds 8 contiguous k at row=(lane&15), k0=(lane>>4)*8
// (m92/m97-verified pattern); D decode per m89: col=lane&15, row=(lane>>4)*4+r.
// ---------------------------------------------------------------------------
#define LDR 40

__global__ __launch_bounds__(256) void gemm_mfma(
    const float* __restrict__ In,
    const float* __restrict__ Wt,
    const float* __restrict__ scale,
    const float* __restrict__ shift,
    const float* __restrict__ resid,
    float* __restrict__ Out,
    int Cin, int O, int P)
{
    const int n    = blockIdx.z;
    const int p0   = blockIdx.x * 128;
    const int o0   = blockIdx.y * 128;
    const int tid  = threadIdx.x;
    const int lane = tid & 63;
    const int wid  = tid >> 6;
    const int wm   = wid >> 1, wn = wid & 1;

    __shared__ short sA[2][128 * LDR];
    __shared__ short sB[2][128 * LDR];

    const float* __restrict__ inn = In + (size_t)n * Cin * P;

    const int ao   = tid >> 1;                        // A row (o_local)
    const int ak   = (tid & 1) * 16;                  // A k base
    const int bp   = (tid & 31) + ((tid >> 6) * 32);  // B row (p_local)
    const int koff = ((tid >> 5) & 1) * 2;            // B k sub-offset
    const int gp   = p0 + bp;
    const bool pok = gp < P;

    float4 ra[4];
    float  rb[16];

    f32x4 acc[4][4];
    #pragma unroll
    for (int i = 0; i < 4; ++i)
        #pragma unroll
        for (int j = 0; j < 4; ++j) acc[i][j] = (f32x4)0.f;

    const int nt = Cin >> 5;

    auto load_regs = [&](int kc) {
        const float* wrow = Wt + (size_t)(o0 + ao) * Cin + kc + ak;
        #pragma unroll
        for (int i = 0; i < 4; ++i)
            ra[i] = *(const float4*)(wrow + i * 4);
        #pragma unroll
        for (int s = 0; s < 8; ++s) {
            int k = kc + s * 4 + koff;
            rb[2 * s]     = pok ? inn[(size_t)k * P + gp]       : 0.f;
            rb[2 * s + 1] = pok ? inn[(size_t)(k + 1) * P + gp] : 0.f;
        }
    };

    auto write_lds = [&](int buf) {
        short* pa = &sA[buf][ao * LDR + ak];
        #pragma unroll
        for (int i = 0; i < 4; ++i) {
            uint2 w = make_uint2(pk2(ra[i].x, ra[i].y), pk2(ra[i].z, ra[i].w));
            *(uint2*)(pa + i * 4) = w;
        }
        short* pb = &sB[buf][bp * LDR];
        #pragma unroll
        for (int s = 0; s < 8; ++s) {
            int k = s * 4 + koff;
            *(unsigned*)(pb + k) = pk2(rb[2 * s], rb[2 * s + 1]);
        }
    };

    auto compute = [&](int buf) {
        const short* pa = &sA[buf][(wm * 64 + (lane & 15)) * LDR + (lane >> 4) * 8];
        const short* pb = &sB[buf][(wn * 64 + (lane & 15)) * LDR + (lane >> 4) * 8];
        bf16x8 af[4], bfr[4];
        #pragma unroll
        for (int i = 0; i < 4; ++i) af[i]  = *(const bf16x8*)(pa + i * 16 * LDR);
        #pragma unroll
        for (int j = 0; j < 4; ++j) bfr[j] = *(const bf16x8*)(pb + j * 16 * LDR);
        #pragma unroll
        for (int i = 0; i < 4; ++i)
            #pragma unroll
            for (int j = 0; j < 4; ++j)
                acc[i][j] = __builtin_amdgcn_mfma_f32_16x16x32_bf16(
                    af[i], bfr[j], acc[i][j], 0, 0, 0);
    };

    load_regs(0);
    write_lds(0);
    for (int t = 0; t < nt; ++t) {
        if (t + 1 < nt) load_regs((t + 1) << 5);
        __syncthreads();
        compute(t & 1);
        if (t + 1 < nt) write_lds((t + 1) & 1);
    }

    // epilogue: BN + residual + ReLU  (D: col=lane&15, row=(lane>>4)*4+r)
    #pragma unroll
    for (int i = 0; i < 4; ++i) {
        #pragma unroll
        for (int r = 0; r < 4; ++r) {
            int o = o0 + wm * 64 + i * 16 + (lane >> 4) * 4 + r;
            float sc = scale[o], sh = shift[o];
            size_t base = ((size_t)n * O + o) * P;
            #pragma unroll
            for (int j = 0; j < 4; ++j) {
                int p = p0 + wn * 64 + j * 16 + (lane & 15);
                if (p < P) {
                    float v = fmaf(acc[i][j][r], sc, sh);
                    if (resid) v += resid[base + p];
                    Out[base + p] = fmaxf(v, 0.f);
                }
            }
        }
    }
}

// ---------------------------------------------------------------------------
// res2net branch step (unchanged, round-1 verified)
// ---------------------------------------------------------------------------
__global__ __launch_bounds__(256) void gcn_step(
    const float* __restrict__ h,
    float* __restrict__ outs,
    const float* __restrict__ gw,
    const float* __restrict__ gb,
    const float* __restrict__ Aadj,
    const float* __restrict__ PAi,
    const float* __restrict__ bscale,
    const float* __restrict__ bshift,
    int step)
{
    const int n  = blockIdx.y;
    const int tt = blockIdx.x;
    const int tid = threadIdx.x;
    const int c  = tid & 31;
    const int tl = tid >> 5;

    __shared__ float sp[32 * 200];
    __shared__ float wsg[96][33];
    __shared__ float Mm[3][25][28];

    const size_t pbase = (size_t)tt * 200;
    const float* hch = h + ((size_t)n * 128 + (size_t)step * 32) * 1600 + pbase;
    const float* pch = (step > 0)
        ? outs + ((size_t)n * 128 + (size_t)(step - 1) * 32) * 1600 + pbase
        : nullptr;

    for (int idx = tid; idx < 32 * 200; idx += 256) {
        int cin = idx / 200, pp = idx % 200;
        float v = hch[(size_t)cin * 1600 + pp];
        if (pch) v += pch[(size_t)cin * 1600 + pp];
        sp[idx] = v;
    }
    for (int idx = tid; idx < 96 * 32; idx += 256)
        wsg[idx >> 5][idx & 31] = gw[idx];
    for (int idx = tid; idx < 3 * 625; idx += 256) {
        int k = idx / 625, rem = idx % 625;
        Mm[k][rem / 25][rem % 25] = Aadj[idx] + PAi[idx];
    }
    __syncthreads();

    float g[3][25];
    {
        float b0 = gb[c], b1 = gb[32 + c], b2 = gb[64 + c];
        #pragma unroll
        for (int v = 0; v < 25; ++v) { g[0][v] = b0; g[1][v] = b1; g[2][v] = b2; }
    }
    for (int cin = 0; cin < 32; ++cin) {
        float w0 = wsg[c][cin], w1 = wsg[32 + c][cin], w2 = wsg[64 + c][cin];
        const float* s = &sp[cin * 200 + tl * 25];
        #pragma unroll
        for (int v = 0; v < 25; ++v) {
            float sv = s[v];
            g[0][v] = fmaf(w0, sv, g[0][v]);
            g[1][v] = fmaf(w1, sv, g[1][v]);
            g[2][v] = fmaf(w2, sv, g[2][v]);
        }
    }

    float out[25];
    #pragma unroll
    for (int w = 0; w < 25; ++w) out[w] = 0.f;
    #pragma unroll
    for (int k = 0; k < 3; ++k)
        #pragma unroll
        for (int v = 0; v < 25; ++v) {
            float gv = g[k][v];
            #pragma unroll
            for (int w = 0; w < 25; ++w)
                out[w] = fmaf(gv, Mm[k][v][w], out[w]);
        }

    float sc = bscale[c], sh = bshift[c];
    __syncthreads();
    #pragma unroll
    for (int w = 0; w < 25; ++w)
        sp[c * 200 + tl * 25 + w] = fmaxf(fmaf(out[w], sc, sh), 0.f);
    __syncthreads();

    float* och = outs + ((size_t)n * 128 + (size_t)step * 32) * 1600 + pbase;
    for (int idx = tid; idx < 32 * 200; idx += 256)
        och[(size_t)(idx / 200) * 1600 + (idx % 200)] = sp[idx];
}

// ---------------------------------------------------------------------------
extern "C" void kernel_launch(void* const* d_in, const int* in_sizes, int n_in,
                              void* d_out, int out_size, void* d_ws, size_t ws_size,
                              hipStream_t stream)
{
    const float* x   = (const float*)d_in[0];
    const float* A   = (const float*)d_in[1];
    const float* rw  = (const float*)d_in[2];
    const float* rwb = (const float*)d_in[3];
    const float* rg  = (const float*)d_in[4];
    const float* rb  = (const float*)d_in[5];
    const float* rm  = (const float*)d_in[6];
    const float* rv  = (const float*)d_in[7];
    const float* gw  = (const float*)d_in[8];
    const float* gb  = (const float*)d_in[9];
    const float* PA  = (const float*)d_in[10];
    const float* bg  = (const float*)d_in[11];
    const float* bb  = (const float*)d_in[12];
    const float* bm  = (const float*)d_in[13];
    const float* bv  = (const float*)d_in[14];
    const float* ew  = (const float*)d_in[15];
    const float* ewb = (const float*)d_in[16];
    const float* eg  = (const float*)d_in[17];
    const float* eb  = (const float*)d_in[18];
    const float* em  = (const float*)d_in[19];
    const float* ev  = (const float*)d_in[20];

    float* wsf  = (float*)d_ws;
    float* h    = wsf;                    // 13,107,200 floats
    float* outs = wsf + 13107200;         // 13,107,200 floats
    float* prm  = wsf + 26214400;         // 1024 floats

    prep_params<<<1, 256, 0, stream>>>(rwb, rg, rb, rm, rv,
                                       ewb, eg, eb, em, ev,
                                       bg, bb, bm, bv, prm);

    // reduct: x[64][256][1600] -> h[64][128][1600]
    gemm_mfma<<<dim3(13, 1, 64), 256, 0, stream>>>(
        x, rw, prm, prm + 128, nullptr, h, 256, 128, 1600);

    for (int i = 0; i < 4; ++i) {
        gcn_step<<<dim3(8, 64), 256, 0, stream>>>(
            h, outs, gw + (size_t)i * 96 * 32, gb + (size_t)i * 96,
            A, PA + (size_t)i * 3 * 625,
            prm + 768 + i * 32, prm + 896 + i * 32, i);
    }

    // expand: outs -> d_out (+x residual)
    gemm_mfma<<<dim3(13, 2, 64), 256, 0, stream>>>(
        outs, ew, prm + 256, prm + 512, x, (float*)d_out, 128, 256, 1600);
}

// Round 5
// 290.330 us; speedup vs baseline: 1.4997x; 1.1728x over previous
//
#include <hip/hip_runtime.h>
#include <cstdint>
#include <cstddef>

#define EPSV 1e-5f

using f32x4  = __attribute__((ext_vector_type(4))) float;
using bf16x8 = __attribute__((ext_vector_type(8))) short;

// RNE pack of two f32 into two bf16 (lo -> low16, hi -> high16)
static __device__ __forceinline__ unsigned pk2(float lo, float hi) {
    unsigned a = __builtin_bit_cast(unsigned, lo);
    unsigned b = __builtin_bit_cast(unsigned, hi);
    a = (a + 0x7FFFu + ((a >> 16) & 1u)) >> 16;
    b = (b + 0x7FFFu + ((b >> 16) & 1u)) & 0xFFFF0000u;
    return a | b;
}

// LDS index swizzle: rows of 32 shorts (64 B). Rows r and r+2 share banks;
// XOR with ((r>>1)&7)<<3 spreads them. Preserves 8-short (16 B) alignment.
static __device__ __forceinline__ int sidx(int row, int k) {
    return (row * 32 + k) ^ (((row >> 1) & 7) << 3);
}

// ---------------------------------------------------------------------------
__global__ __launch_bounds__(256) void prep_params(
    const float* __restrict__ rwb, const float* __restrict__ rg,
    const float* __restrict__ rb,  const float* __restrict__ rm,
    const float* __restrict__ rv,
    const float* __restrict__ ewb, const float* __restrict__ eg,
    const float* __restrict__ eb,  const float* __restrict__ em,
    const float* __restrict__ ev,
    const float* __restrict__ bg,  const float* __restrict__ bb,
    const float* __restrict__ bm,  const float* __restrict__ bv,
    float* __restrict__ prm)
{
    int t = threadIdx.x;
    if (t < 128) {
        float sc = rg[t] * rsqrtf(rv[t] + EPSV);
        prm[t]       = sc;
        prm[128 + t] = rb[t] - rm[t] * sc + rwb[t] * sc;
        float bsc = bg[t] * rsqrtf(bv[t] + EPSV);
        prm[768 + t] = bsc;
        prm[896 + t] = bb[t] - bm[t] * bsc;
    }
    {
        float sc = eg[t] * rsqrtf(ev[t] + EPSV);
        prm[256 + t] = sc;
        prm[512 + t] = eb[t] - em[t] * sc + ewb[t] * sc;
    }
}

// ---------------------------------------------------------------------------
// bf16 MFMA batched GEMM + BN + (residual) + ReLU.
// In  [NB][Cin][P] f32, Wt [O][Cin] f32, Out [NB][O][P] f32.
// 256 thr (4 waves 2x2: wave = 64 o x 32 p), tile BM=128 x BN=64, BK=32,
// double-buffered swizzled LDS. Requires P % 64 == 0, Cin % 32 == 0.
// Fragments: lane holds 8 contiguous k at row=(lane&15), k0=(lane>>4)*8;
// D decode (m89): col=lane&15, row=(lane>>4)*4+r.
// ---------------------------------------------------------------------------
__global__ __launch_bounds__(256) void gemm_mfma(
    const float* __restrict__ In,
    const float* __restrict__ Wt,
    const float* __restrict__ scale,
    const float* __restrict__ shift,
    const float* __restrict__ resid,
    float* __restrict__ Out,
    int Cin, int O, int P)
{
    const int n    = blockIdx.z;
    const int p0   = blockIdx.x * 64;
    const int o0   = blockIdx.y * 128;
    const int tid  = threadIdx.x;
    const int lane = tid & 63;
    const int wid  = tid >> 6;
    const int wm   = wid >> 1, wn = wid & 1;

    __shared__ short sA[2][128 * 32];   // [o][k] swizzled
    __shared__ short sB[2][64 * 32];    // [p][k] swizzled

    const float* __restrict__ inn = In + (size_t)n * Cin * P;

    // A staging: thread -> row ao = tid>>1 (0..127), k base ak = (tid&1)*16
    const int ao = tid >> 1;
    const int ak = (tid & 1) * 16;
    // B staging: thread -> p = tid&63, k base kb = (tid>>6)*8
    const int bp = tid & 63;
    const int kb = (tid >> 6) * 8;
    const int gp = p0 + bp;

    float4 ra[4];
    float  rbv[8];

    f32x4 acc[4][2];
    #pragma unroll
    for (int i = 0; i < 4; ++i)
        #pragma unroll
        for (int j = 0; j < 2; ++j) acc[i][j] = (f32x4)0.f;

    const int nt = Cin >> 5;

    auto load_regs = [&](int kc) {
        const float* wrow = Wt + (size_t)(o0 + ao) * Cin + kc + ak;
        #pragma unroll
        for (int i = 0; i < 4; ++i)
            ra[i] = *(const float4*)(wrow + i * 4);
        #pragma unroll
        for (int j = 0; j < 8; ++j)
            rbv[j] = inn[(size_t)(kc + kb + j) * P + gp];
    };

    auto write_lds = [&](int buf) {
        // A: 16 contiguous k -> 2 x ds_write_b128
        uint4 w0 = make_uint4(pk2(ra[0].x, ra[0].y), pk2(ra[0].z, ra[0].w),
                              pk2(ra[1].x, ra[1].y), pk2(ra[1].z, ra[1].w));
        uint4 w1 = make_uint4(pk2(ra[2].x, ra[2].y), pk2(ra[2].z, ra[2].w),
                              pk2(ra[3].x, ra[3].y), pk2(ra[3].z, ra[3].w));
        *(uint4*)(&sA[buf][sidx(ao, ak)])     = w0;
        *(uint4*)(&sA[buf][sidx(ao, ak + 8)]) = w1;
        // B: 8 contiguous k -> 1 x ds_write_b128
        uint4 wb = make_uint4(pk2(rbv[0], rbv[1]), pk2(rbv[2], rbv[3]),
                              pk2(rbv[4], rbv[5]), pk2(rbv[6], rbv[7]));
        *(uint4*)(&sB[buf][sidx(bp, kb)]) = wb;
    };

    auto compute = [&](int buf) {
        const int rl = lane & 15;
        const int k0 = (lane >> 4) * 8;
        bf16x8 af[4], bfr[2];
        #pragma unroll
        for (int i = 0; i < 4; ++i)
            af[i]  = *(const bf16x8*)(&sA[buf][sidx(wm * 64 + i * 16 + rl, k0)]);
        #pragma unroll
        for (int j = 0; j < 2; ++j)
            bfr[j] = *(const bf16x8*)(&sB[buf][sidx(wn * 32 + j * 16 + rl, k0)]);
        #pragma unroll
        for (int i = 0; i < 4; ++i)
            #pragma unroll
            for (int j = 0; j < 2; ++j)
                acc[i][j] = __builtin_amdgcn_mfma_f32_16x16x32_bf16(
                    af[i], bfr[j], acc[i][j], 0, 0, 0);
    };

    load_regs(0);
    write_lds(0);
    for (int t = 0; t < nt; ++t) {
        if (t + 1 < nt) load_regs((t + 1) << 5);
        __syncthreads();
        compute(t & 1);
        if (t + 1 < nt) write_lds((t + 1) & 1);
    }

    // epilogue: BN + residual + ReLU
    #pragma unroll
    for (int i = 0; i < 4; ++i) {
        #pragma unroll
        for (int r = 0; r < 4; ++r) {
            int o = o0 + wm * 64 + i * 16 + (lane >> 4) * 4 + r;
            float sc = scale[o], sh = shift[o];
            size_t base = ((size_t)n * O + o) * P;
            #pragma unroll
            for (int j = 0; j < 2; ++j) {
                int p = p0 + wn * 32 + j * 16 + (lane & 15);
                float v = fmaf(acc[i][j][r], sc, sh);
                if (resid) v += resid[base + p];
                Out[base + p] = fmaxf(v, 0.f);
            }
        }
    }
}

// ---------------------------------------------------------------------------
// res2net branch step (unchanged, verified)
// ---------------------------------------------------------------------------
__global__ __launch_bounds__(256) void gcn_step(
    const float* __restrict__ h,
    float* __restrict__ outs,
    const float* __restrict__ gw,
    const float* __restrict__ gb,
    const float* __restrict__ Aadj,
    const float* __restrict__ PAi,
    const float* __restrict__ bscale,
    const float* __restrict__ bshift,
    int step)
{
    const int n  = blockIdx.y;
    const int tt = blockIdx.x;
    const int tid = threadIdx.x;
    const int c  = tid & 31;
    const int tl = tid >> 5;

    __shared__ float sp[32 * 200];
    __shared__ float wsg[96][33];
    __shared__ float Mm[3][25][28];

    const size_t pbase = (size_t)tt * 200;
    const float* hch = h + ((size_t)n * 128 + (size_t)step * 32) * 1600 + pbase;
    const float* pch = (step > 0)
        ? outs + ((size_t)n * 128 + (size_t)(step - 1) * 32) * 1600 + pbase
        : nullptr;

    for (int idx = tid; idx < 32 * 200; idx += 256) {
        int cin = idx / 200, pp = idx % 200;
        float v = hch[(size_t)cin * 1600 + pp];
        if (pch) v += pch[(size_t)cin * 1600 + pp];
        sp[idx] = v;
    }
    for (int idx = tid; idx < 96 * 32; idx += 256)
        wsg[idx >> 5][idx & 31] = gw[idx];
    for (int idx = tid; idx < 3 * 625; idx += 256) {
        int k = idx / 625, rem = idx % 625;
        Mm[k][rem / 25][rem % 25] = Aadj[idx] + PAi[idx];
    }
    __syncthreads();

    float g[3][25];
    {
        float b0 = gb[c], b1 = gb[32 + c], b2 = gb[64 + c];
        #pragma unroll
        for (int v = 0; v < 25; ++v) { g[0][v] = b0; g[1][v] = b1; g[2][v] = b2; }
    }
    for (int cin = 0; cin < 32; ++cin) {
        float w0 = wsg[c][cin], w1 = wsg[32 + c][cin], w2 = wsg[64 + c][cin];
        const float* s = &sp[cin * 200 + tl * 25];
        #pragma unroll
        for (int v = 0; v < 25; ++v) {
            float sv = s[v];
            g[0][v] = fmaf(w0, sv, g[0][v]);
            g[1][v] = fmaf(w1, sv, g[1][v]);
            g[2][v] = fmaf(w2, sv, g[2][v]);
        }
    }

    float out[25];
    #pragma unroll
    for (int w = 0; w < 25; ++w) out[w] = 0.f;
    #pragma unroll
    for (int k = 0; k < 3; ++k)
        #pragma unroll
        for (int v = 0; v < 25; ++v) {
            float gv = g[k][v];
            #pragma unroll
            for (int w = 0; w < 25; ++w)
                out[w] = fmaf(gv, Mm[k][v][w], out[w]);
        }

    float sc = bscale[c], sh = bshift[c];
    __syncthreads();
    #pragma unroll
    for (int w = 0; w < 25; ++w)
        sp[c * 200 + tl * 25 + w] = fmaxf(fmaf(out[w], sc, sh), 0.f);
    __syncthreads();

    float* och = outs + ((size_t)n * 128 + (size_t)step * 32) * 1600 + pbase;
    for (int idx = tid; idx < 32 * 200; idx += 256)
        och[(size_t)(idx / 200) * 1600 + (idx % 200)] = sp[idx];
}

// ---------------------------------------------------------------------------
extern "C" void kernel_launch(void* const* d_in, const int* in_sizes, int n_in,
                              void* d_out, int out_size, void* d_ws, size_t ws_size,
                              hipStream_t stream)
{
    const float* x   = (const float*)d_in[0];
    const float* A   = (const float*)d_in[1];
    const float* rw  = (const float*)d_in[2];
    const float* rwb = (const float*)d_in[3];
    const float* rg  = (const float*)d_in[4];
    const float* rb  = (const float*)d_in[5];
    const float* rm  = (const float*)d_in[6];
    const float* rv  = (const float*)d_in[7];
    const float* gw  = (const float*)d_in[8];
    const float* gb  = (const float*)d_in[9];
    const float* PA  = (const float*)d_in[10];
    const float* bg  = (const float*)d_in[11];
    const float* bb  = (const float*)d_in[12];
    const float* bm  = (const float*)d_in[13];
    const float* bv  = (const float*)d_in[14];
    const float* ew  = (const float*)d_in[15];
    const float* ewb = (const float*)d_in[16];
    const float* eg  = (const float*)d_in[17];
    const float* eb  = (const float*)d_in[18];
    const float* em  = (const float*)d_in[19];
    const float* ev  = (const float*)d_in[20];

    float* wsf  = (float*)d_ws;
    float* h    = wsf;                    // 13,107,200 floats
    float* outs = wsf + 13107200;         // 13,107,200 floats
    float* prm  = wsf + 26214400;         // 1024 floats

    prep_params<<<1, 256, 0, stream>>>(rwb, rg, rb, rm, rv,
                                       ewb, eg, eb, em, ev,
                                       bg, bb, bm, bv, prm);

    // reduct: x[64][256][1600] -> h[64][128][1600]
    gemm_mfma<<<dim3(25, 1, 64), 256, 0, stream>>>(
        x, rw, prm, prm + 128, nullptr, h, 256, 128, 1600);

    for (int i = 0; i < 4; ++i) {
        gcn_step<<<dim3(8, 64), 256, 0, stream>>>(
            h, outs, gw + (size_t)i * 96 * 32, gb + (size_t)i * 96,
            A, PA + (size_t)i * 3 * 625,
            prm + 768 + i * 32, prm + 896 + i * 32, i);
    }

    // expand: outs -> d_out (+x residual)
    gemm_mfma<<<dim3(25, 2, 64), 256, 0, stream>>>(
        outs, ew, prm + 256, prm + 512, x, (float*)d_out, 128, 256, 1600);
}